// Round 4
// baseline (139.002 us; speedup 1.0000x reference)
//
#include <hip/hip_runtime.h>
#include <math.h>

#define PMAX 22
#define HID 64
#define OUTD 128
#define SETS_PER_WAVE 8
#define WAVES_PER_BLOCK 4

// Broadcast one lane's float to all lanes via SGPR (uniform lane index).
__device__ __forceinline__ float rl(float v, int l) {
    return __int_as_float(__builtin_amdgcn_readlane(__float_as_int(v), l));
}

__global__ __launch_bounds__(256) void set_encoder_kernel(
    const float* __restrict__ player_locs,  // [B,22,2]
    const float* __restrict__ actor_locs,   // [B,2]
    const float* __restrict__ flags,        // [B,22,2]
    const int*   __restrict__ mask,         // [B,22]
    const float* __restrict__ W1,           // [6,64]
    const float* __restrict__ b1,           // [64]
    const float* __restrict__ W2,           // [64,128]
    const float* __restrict__ b2,           // [128]
    float* __restrict__ out)                // [B,128]
{
    const int tid  = threadIdx.x;
    const int lane = tid & 63;
    const int wave = tid >> 6;

    const int wave_id = blockIdx.x * WAVES_PER_BLOCK + wave;
    const int set0    = wave_id * SETS_PER_WAVE;

    // --- per-lane W1 column + bias (lane = hidden unit) ---
    const float w10 = W1[0 * HID + lane];
    const float w11 = W1[1 * HID + lane];
    const float w12 = W1[2 * HID + lane];
    const float w13 = W1[3 * HID + lane];
    const float w14 = W1[4 * HID + lane];
    const float w15 = W1[5 * HID + lane];
    const float b1l = b1[lane];

    // --- phase 0: features into REGISTERS, no LDS.
    // Iteration g loads the 44 contiguous player-rows of sets (2g, 2g+1)
    // into lanes 0..43 (coalesced); lanes 44..63 compute garbage (clamped,
    // never read). Validity bitmask per pair via ballot.
    float fr[4][6];
    unsigned long long bm[4];
#pragma unroll
    for (int g = 0; g < 4; ++g) {
        const int lidx = lane < 2 * PMAX ? lane : 2 * PMAX - 1;  // clamp
        const int grow = (set0 + 2 * g) * PMAX + lidx;           // global row
        float2 pl = ((const float2*)player_locs)[grow];
        float2 fl = ((const float2*)flags)[grow];
        int    m  = mask[grow];
        const int sl = 2 * g + (lidx >= PMAX ? 1 : 0);
        float2 ac = ((const float2*)actor_locs)[set0 + sl];
        float dx = pl.x - ac.x;
        float dy = pl.y - ac.y;
        fr[g][0] = dx;
        fr[g][1] = dy;
        fr[g][2] = sqrtf(dx * dx + dy * dy);
        fr[g][3] = atan2f(dy, dx);
        fr[g][4] = fl.x;
        fr[g][5] = fl.y;
        bm[g] = __ballot((lane < 2 * PMAX) && (m != 0));
    }

    // --- phase 1: layer1 + masked pool; lane = hidden unit.
    // SGPR bitmask skip-loop; features broadcast via readlane (uniform src).
    float hs[SETS_PER_WAVE];
    unsigned nonempty = 0;
#pragma unroll
    for (int s = 0; s < SETS_PER_WAVE; ++s) {
        const int g    = s >> 1;              // constant after unroll
        const int base = (s & 1) * PMAX;      // 0 or 22
        unsigned bits = (unsigned)(bm[g] >> base) & 0x3FFFFFu;
        const int cnt = __builtin_popcount(bits);
        if (bits) nonempty |= (1u << s);
        float acc = 0.0f;
        unsigned bb = bits;
        while (bb) {
            const int p = __builtin_ctz(bb);
            bb &= bb - 1;
            const int src = base + p;         // uniform lane index
            float f0 = rl(fr[g][0], src);
            float f1 = rl(fr[g][1], src);
            float f2 = rl(fr[g][2], src);
            float f3 = rl(fr[g][3], src);
            float f4 = rl(fr[g][4], src);
            float f5 = rl(fr[g][5], src);
            float t0 = fmaf(f0, w10, b1l);
            t0 = fmaf(f1, w11, t0);
            t0 = fmaf(f2, w12, t0);
            float t1 = f3 * w13;
            t1 = fmaf(f4, w14, t1);
            t1 = fmaf(f5, w15, t1);
            acc += fmaxf(t0 + t1, 0.0f);
        }
        hs[s] = acc * (1.0f / fmaxf((float)cnt, 1.0f));
    }

    // --- phase 2: out[8 sets][2 cols/lane] = hbar @ W2.
    // Lane k holds hbar[k][s] in hs[] -> broadcast via readlane per k.
    float a0[SETS_PER_WAVE], a1[SETS_PER_WAVE];
#pragma unroll
    for (int s = 0; s < SETS_PER_WAVE; ++s) { a0[s] = 0.0f; a1[s] = 0.0f; }

    const float2* w2p = (const float2*)W2;  // [64][64] float2; lane owns col pair
    float2 w2v = w2p[lane];                 // k=0 prefetch
#pragma unroll 8
    for (int k = 0; k < HID; ++k) {
        const float2 cur = w2v;
        w2v = w2p[(((k + 1) & 63) * 64) + lane];  // next-k prefetch (wraps)
        const float h0 = rl(hs[0], k);
        const float h1 = rl(hs[1], k);
        const float h2 = rl(hs[2], k);
        const float h3 = rl(hs[3], k);
        const float h4 = rl(hs[4], k);
        const float h5 = rl(hs[5], k);
        const float h6 = rl(hs[6], k);
        const float h7 = rl(hs[7], k);
        a0[0] = fmaf(h0, cur.x, a0[0]); a1[0] = fmaf(h0, cur.y, a1[0]);
        a0[1] = fmaf(h1, cur.x, a0[1]); a1[1] = fmaf(h1, cur.y, a1[1]);
        a0[2] = fmaf(h2, cur.x, a0[2]); a1[2] = fmaf(h2, cur.y, a1[2]);
        a0[3] = fmaf(h3, cur.x, a0[3]); a1[3] = fmaf(h3, cur.y, a1[3]);
        a0[4] = fmaf(h4, cur.x, a0[4]); a1[4] = fmaf(h4, cur.y, a1[4]);
        a0[5] = fmaf(h5, cur.x, a0[5]); a1[5] = fmaf(h5, cur.y, a1[5]);
        a0[6] = fmaf(h6, cur.x, a0[6]); a1[6] = fmaf(h6, cur.y, a1[6]);
        a0[7] = fmaf(h7, cur.x, a0[7]); a1[7] = fmaf(h7, cur.y, a1[7]);
    }

    // --- epilogue: + b2 * [cnt>0], coalesced float2 stores ---
    const float2 b2v = *(const float2*)&b2[2 * lane];
#pragma unroll
    for (int s = 0; s < SETS_PER_WAVE; ++s) {
        const float f = (nonempty >> s) & 1u ? 1.0f : 0.0f;
        float2 o;
        o.x = a0[s] + f * b2v.x;
        o.y = a1[s] + f * b2v.y;
        ((float2*)out)[(size_t)(set0 + s) * (OUTD / 2) + lane] = o;
    }
}

extern "C" void kernel_launch(void* const* d_in, const int* in_sizes, int n_in,
                              void* d_out, int out_size, void* d_ws, size_t ws_size,
                              hipStream_t stream) {
    const float* player_locs = (const float*)d_in[0];
    const float* actor_locs  = (const float*)d_in[1];
    const float* flags       = (const float*)d_in[2];
    const int*   mask        = (const int*)d_in[3];
    const float* W1          = (const float*)d_in[4];
    const float* b1          = (const float*)d_in[5];
    const float* W2          = (const float*)d_in[6];
    const float* b2          = (const float*)d_in[7];
    float*       out         = (float*)d_out;

    const int B = in_sizes[0] / (PMAX * 2);  // 65536
    const int sets_per_block = WAVES_PER_BLOCK * SETS_PER_WAVE;  // 32
    const int grid = (B + sets_per_block - 1) / sets_per_block;  // 2048

    hipLaunchKernelGGL(set_encoder_kernel, dim3(grid), dim3(256), 0, stream,
                       player_locs, actor_locs, flags, mask, W1, b1, W2, b2, out);
}

// Round 6
// 122.340 us; speedup vs baseline: 1.1362x; 1.1362x over previous
//
#include <hip/hip_runtime.h>
#include <math.h>

#define PMAX 22
#define HID 64
#define OUTD 128
#define SETS_PER_WAVE 8
#define WAVES_PER_BLOCK 4

typedef __attribute__((ext_vector_type(8))) short short8;
typedef __attribute__((ext_vector_type(4))) float float4v;

// Broadcast one lane's float to all lanes via SGPR (uniform lane index).
__device__ __forceinline__ float rl(float v, int l) {
    return __int_as_float(__builtin_amdgcn_readlane(__float_as_int(v), l));
}
// fp32 -> bf16 bits, round-to-nearest-even
__device__ __forceinline__ unsigned bf16_bits(float x) {
    unsigned u = __float_as_uint(x);
    return (u + 0x7FFFu + ((u >> 16) & 1u)) >> 16;
}
// Wave-internal LDS sync (per-wave hb slice only).
__device__ __forceinline__ void wave_lds_sync() {
    asm volatile("s_waitcnt lgkmcnt(0)" ::: "memory");
    __builtin_amdgcn_wave_barrier();
}

__global__ __launch_bounds__(256) void set_encoder_kernel(
    const float* __restrict__ player_locs,  // [B,22,2]
    const float* __restrict__ actor_locs,   // [B,2]
    const float* __restrict__ flags,        // [B,22,2]
    const int*   __restrict__ mask,         // [B,22]
    const float* __restrict__ W1,           // [6,64]
    const float* __restrict__ b1,           // [64]
    const float* __restrict__ W2,           // [64,128]
    const float* __restrict__ b2,           // [128]
    float* __restrict__ out)                // [B,128]
{
    // B-fragments of W2, packed bf16 pairs. Frag f dword (f*256 + 4*lane + j)
    // holds ( W2[32kt+8Q+2j][16nt+c], W2[...+1][...] ) for f=kt*8+nt,
    // lane=Q*16+c — so one ds_read_b128 per lane yields the whole fragment.
    __shared__ __align__(16) unsigned w2f[16 * 256];                       // 16 KB
    __shared__ __align__(16) unsigned short hb[WAVES_PER_BLOCK][SETS_PER_WAVE][HID + 4];

    const int tid  = threadIdx.x;
    const int lane = tid & 63;
    const int wave = tid >> 6;

    const int wave_id = blockIdx.x * WAVES_PER_BLOCK + wave;
    const int set0    = wave_id * SETS_PER_WAVE;

    // --- W2 -> LDS B-fragments (block-cooperative, one-time) ---
    {
        const int pr = tid >> 3;   // k-pair 0..31 (rows 2pr, 2pr+1)
        const int nt = tid & 7;    // n-tile 0..7 (cols 16nt..16nt+15)
        const float* rA = W2 + (size_t)(2 * pr) * OUTD + 16 * nt;
        const float* rB = rA + OUTD;
        float ra[16], rb[16];
#pragma unroll
        for (int i = 0; i < 4; ++i) {
            *(float4*)&ra[4 * i] = ((const float4*)rA)[i];
            *(float4*)&rb[4 * i] = ((const float4*)rB)[i];
        }
        const int kt = pr >> 4;
        const int kk = (2 * pr) & 31;       // 8Q + 2j2
        const int Q  = kk >> 3;
        const int j2 = (kk >> 1) & 3;
        const int base = ((kt * 8 + nt) * 4 + Q) * 64 + j2;
#pragma unroll
        for (int c = 0; c < 16; ++c)
            w2f[base + 4 * c] = bf16_bits(ra[c]) | (bf16_bits(rb[c]) << 16);
    }

    // --- per-lane W1 column + bias (lane = hidden unit) ---
    const float w10 = W1[0 * HID + lane];
    const float w11 = W1[1 * HID + lane];
    const float w12 = W1[2 * HID + lane];
    const float w13 = W1[3 * HID + lane];
    const float w14 = W1[4 * HID + lane];
    const float w15 = W1[5 * HID + lane];
    const float b1l = b1[lane];

    __syncthreads();  // w2f visible to all waves (only block barrier)

    // --- phase 0: features into registers; validity via ballot ---
    float fr[4][6];
    unsigned long long bm[4];
#pragma unroll
    for (int g = 0; g < 4; ++g) {
        const int lidx = lane < 2 * PMAX ? lane : 2 * PMAX - 1;  // clamp
        const int grow = (set0 + 2 * g) * PMAX + lidx;
        float2 pl = ((const float2*)player_locs)[grow];
        float2 fl = ((const float2*)flags)[grow];
        int    m  = mask[grow];
        const int sl = 2 * g + (lidx >= PMAX ? 1 : 0);
        float2 ac = ((const float2*)actor_locs)[set0 + sl];
        float dx = pl.x - ac.x;
        float dy = pl.y - ac.y;
        fr[g][0] = dx;
        fr[g][1] = dy;
        fr[g][2] = sqrtf(dx * dx + dy * dy);
        fr[g][3] = atan2f(dy, dx);
        fr[g][4] = fl.x;
        fr[g][5] = fl.y;
        bm[g] = __ballot((lane < 2 * PMAX) && (m != 0));
    }

    // --- phase 1: layer1 + masked pool; lane = hidden unit; SGPR bitmask
    //     skip-loop with readlane feature broadcast ---
    float hs[SETS_PER_WAVE];
    unsigned nonempty = 0;
#pragma unroll
    for (int s = 0; s < SETS_PER_WAVE; ++s) {
        const int g    = s >> 1;
        const int base = (s & 1) * PMAX;
        unsigned bits = (unsigned)(bm[g] >> base) & 0x3FFFFFu;
        const int cnt = __builtin_popcount(bits);
        if (bits) nonempty |= (1u << s);
        float acc = 0.0f;
        unsigned bb = bits;
        while (bb) {
            const int p = __builtin_ctz(bb);
            bb &= bb - 1;
            const int src = base + p;
            float f0 = rl(fr[g][0], src);
            float f1 = rl(fr[g][1], src);
            float f2 = rl(fr[g][2], src);
            float f3 = rl(fr[g][3], src);
            float f4 = rl(fr[g][4], src);
            float f5 = rl(fr[g][5], src);
            float t0 = fmaf(f0, w10, b1l);
            t0 = fmaf(f1, w11, t0);
            t0 = fmaf(f2, w12, t0);
            float t1 = f3 * w13;
            t1 = fmaf(f4, w14, t1);
            t1 = fmaf(f5, w15, t1);
            acc += fmaxf(t0 + t1, 0.0f);
        }
        hs[s] = acc * (1.0f / fmaxf((float)cnt, 1.0f));  // pool scale folded in
    }

    // --- stage h-bar to LDS as bf16: hb[wave][s][k], lane = k (per-wave) ---
#pragma unroll
    for (int s = 0; s < SETS_PER_WAVE; ++s)
        hb[wave][s][lane] = (unsigned short)bf16_bits(hs[s]);
    wave_lds_sync();

    // --- phase 2: out[16x128] = hbar @ W2 via MFMA (rows 8..15 dup, unstored)
    // A-frag: lane l holds A[m=lane&15][k=(lane>>4)*8+j] (m89-verified).
    const int Q  = lane >> 4;
    const int sA = lane & 7;
    short8 afrag[2];
#pragma unroll
    for (int kt = 0; kt < 2; ++kt) {
        uint2 p0 = *(const uint2*)&hb[wave][sA][32 * kt + 8 * Q];
        uint2 p1 = *(const uint2*)&hb[wave][sA][32 * kt + 8 * Q + 4];
        union { unsigned u[4]; short8 s8; } cv;
        cv.u[0] = p0.x; cv.u[1] = p0.y; cv.u[2] = p1.x; cv.u[3] = p1.y;
        afrag[kt] = cv.s8;
    }

    float4v acc[8];
#pragma unroll
    for (int nt = 0; nt < 8; ++nt) {
        union { uint4 u4; short8 s8; } f0, f1;
        f0.u4 = *(const uint4*)&w2f[(0 * 8 + nt) * 256 + 4 * lane];
        f1.u4 = *(const uint4*)&w2f[(1 * 8 + nt) * 256 + 4 * lane];
        float4v z = {0.0f, 0.0f, 0.0f, 0.0f};
        acc[nt] = __builtin_amdgcn_mfma_f32_16x16x32_bf16(afrag[0], f0.s8, z, 0, 0, 0);
        acc[nt] = __builtin_amdgcn_mfma_f32_16x16x32_bf16(afrag[1], f1.s8, acc[nt], 0, 0, 0);
    }

    // --- epilogue: + b2 * [cnt>0]; C layout row=(lane>>4)*4+r (=set), col=lane&15
    const int c = lane & 15;
    float b2v[8];
#pragma unroll
    for (int nt = 0; nt < 8; ++nt) b2v[nt] = b2[16 * nt + c];

    if (Q < 2) {
        const unsigned nsh = nonempty >> (4 * Q);
#pragma unroll
        for (int nt = 0; nt < 8; ++nt) {
#pragma unroll
            for (int r = 0; r < 4; ++r) {
                const int s = 4 * Q + r;
                const float f = (float)((nsh >> r) & 1u);
                out[(size_t)(set0 + s) * OUTD + 16 * nt + c] = acc[nt][r] + f * b2v[nt];
            }
        }
    }
}

extern "C" void kernel_launch(void* const* d_in, const int* in_sizes, int n_in,
                              void* d_out, int out_size, void* d_ws, size_t ws_size,
                              hipStream_t stream) {
    const float* player_locs = (const float*)d_in[0];
    const float* actor_locs  = (const float*)d_in[1];
    const float* flags       = (const float*)d_in[2];
    const int*   mask        = (const int*)d_in[3];
    const float* W1          = (const float*)d_in[4];
    const float* b1          = (const float*)d_in[5];
    const float* W2          = (const float*)d_in[6];
    const float* b2          = (const float*)d_in[7];
    float*       out         = (float*)d_out;

    const int B = in_sizes[0] / (PMAX * 2);  // 65536
    const int sets_per_block = WAVES_PER_BLOCK * SETS_PER_WAVE;  // 32
    const int grid = (B + sets_per_block - 1) / sets_per_block;  // 2048

    hipLaunchKernelGGL(set_encoder_kernel, dim3(grid), dim3(256), 0, stream,
                       player_locs, actor_locs, flags, mask, W1, b1, W2, b2, out);
}

// Round 8
// 112.576 us; speedup vs baseline: 1.2347x; 1.0867x over previous
//
#include <hip/hip_runtime.h>
#include <math.h>

#define PMAX 22
#define HID 64
#define OUTD 128
#define SETS_PER_WAVE 8
#define WAVES_PER_BLOCK 4

typedef __attribute__((ext_vector_type(8))) short short8;
typedef __attribute__((ext_vector_type(4))) float float4v;
typedef _Float16 fh2 __attribute__((ext_vector_type(2)));

__device__ __forceinline__ int rl_i(int v, int l) {
    return __builtin_amdgcn_readlane(v, l);
}
// pack two fp32 -> f16x2 bits (v_cvt_pkrtz_f16_f32)
__device__ __forceinline__ int pk2(float x, float y) {
    auto v = __builtin_amdgcn_cvt_pkrtz(x, y);
    union { decltype(v) h; int i; } c;
    c.h = v;
    return c.i;
}
// f16x2 dot-product accumulate: c += a.x*b.x + a.y*b.y (v_dot2_f32_f16)
__device__ __forceinline__ float fdot2i(int a, int b, float c) {
    union { int i; fh2 h; } ua, ub;
    ua.i = a;
    ub.i = b;
#if defined(__has_builtin) && __has_builtin(__builtin_amdgcn_fdot2)
    return __builtin_amdgcn_fdot2(ua.h, ub.h, c, false);
#else
    return fmaf((float)ua.h.x, (float)ub.h.x, fmaf((float)ua.h.y, (float)ub.h.y, c));
#endif
}
// fp32 -> bf16 bits, round-to-nearest-even
__device__ __forceinline__ unsigned bf16_bits(float x) {
    unsigned u = __float_as_uint(x);
    return (u + 0x7FFFu + ((u >> 16) & 1u)) >> 16;
}
// Wave-internal LDS sync (per-wave hb slice only).
__device__ __forceinline__ void wave_lds_sync() {
    asm volatile("s_waitcnt lgkmcnt(0)" ::: "memory");
    __builtin_amdgcn_wave_barrier();
}
// Fast atan2: |err| ~1e-4 rad, ~13 VALU. Degree-7 odd minimax on [0,1].
__device__ __forceinline__ float fast_atan2(float y, float x) {
    float ax = fabsf(x), ay = fabsf(y);
    float mn = fminf(ax, ay), mx = fmaxf(ax, ay);
    float a = mn * __builtin_amdgcn_rcpf(fmaxf(mx, 1e-30f));
    float s = a * a;
    float r = a * fmaf(s, fmaf(s, fmaf(s, -0.0851330f, 0.1801410f), -0.3302995f), 0.9998660f);
    if (ay > ax) r = 1.57079637f - r;
    if (x < 0.0f) r = 3.14159274f - r;
    return copysignf(r, y);
}

__global__ __launch_bounds__(256) void set_encoder_kernel(
    const float* __restrict__ player_locs,  // [B,22,2]
    const float* __restrict__ actor_locs,   // [B,2]
    const float* __restrict__ flags,        // [B,22,2]
    const int*   __restrict__ mask,         // [B,22]
    const float* __restrict__ W1,           // [6,64]
    const float* __restrict__ b1,           // [64]
    const float* __restrict__ W2,           // [64,128]
    const float* __restrict__ b2,           // [128]
    float* __restrict__ out)                // [B,128]
{
    // B-fragments of W2, packed bf16 pairs (one ds_read_b128 per lane/frag).
    __shared__ __align__(16) unsigned w2f[16 * 256];                       // 16 KB
    __shared__ __align__(16) unsigned short hb[WAVES_PER_BLOCK][SETS_PER_WAVE][HID + 4];

    const int tid  = threadIdx.x;
    const int lane = tid & 63;
    const int wave = tid >> 6;

    const int wave_id = blockIdx.x * WAVES_PER_BLOCK + wave;
    const int set0    = wave_id * SETS_PER_WAVE;

    // --- W2 -> LDS B-fragments (block-cooperative, one-time) ---
    {
        const int pr = tid >> 3;   // k-pair 0..31 (rows 2pr, 2pr+1)
        const int nt = tid & 7;    // n-tile 0..7
        const float* rA = W2 + (size_t)(2 * pr) * OUTD + 16 * nt;
        const float* rB = rA + OUTD;
        float ra[16], rb[16];
#pragma unroll
        for (int i = 0; i < 4; ++i) {
            *(float4*)&ra[4 * i] = ((const float4*)rA)[i];
            *(float4*)&rb[4 * i] = ((const float4*)rB)[i];
        }
        const int kt = pr >> 4;
        const int kk = (2 * pr) & 31;
        const int Q  = kk >> 3;
        const int j2 = (kk >> 1) & 3;
        const int base = ((kt * 8 + nt) * 4 + Q) * 64 + j2;
#pragma unroll
        for (int c = 0; c < 16; ++c)
            w2f[base + 4 * c] = bf16_bits(ra[c]) | (bf16_bits(rb[c]) << 16);
    }

    // --- per-lane W1 column + bias, packed to f16x2 (lane = hidden unit) ---
    const int w01 = pk2(W1[0 * HID + lane], W1[1 * HID + lane]);
    const int w23 = pk2(W1[2 * HID + lane], W1[3 * HID + lane]);
    const int w45 = pk2(W1[4 * HID + lane], W1[5 * HID + lane]);
    const float b1l = b1[lane];

    __syncthreads();  // w2f visible to all waves (only block barrier)

    // --- phase 0: features into packed-f16x2 registers; validity via ballot ---
    int fh[4][3];
    unsigned long long bm[4];
#pragma unroll
    for (int g = 0; g < 4; ++g) {
        const int lidx = lane < 2 * PMAX ? lane : 2 * PMAX - 1;  // clamp
        const int grow = (set0 + 2 * g) * PMAX + lidx;
        float2 pl = ((const float2*)player_locs)[grow];
        float2 fl = ((const float2*)flags)[grow];
        int    m  = mask[grow];
        const int sl = 2 * g + (lidx >= PMAX ? 1 : 0);
        float2 ac = ((const float2*)actor_locs)[set0 + sl];
        float dx = pl.x - ac.x;
        float dy = pl.y - ac.y;
        float dist = __builtin_amdgcn_sqrtf(fmaf(dx, dx, dy * dy));
        float ang  = fast_atan2(dy, dx);
        fh[g][0] = pk2(dx, dy);
        fh[g][1] = pk2(dist, ang);
        fh[g][2] = pk2(fl.x, fl.y);
        bm[g] = __ballot((lane < 2 * PMAX) && (m != 0));
    }

    // --- phase 1: layer1 + masked pool; lane = hidden unit; SGPR bitmask
    //     skip-loop; per player: 3 readlane + 3 v_dot2_f32_f16 + max + add ---
    float hs[SETS_PER_WAVE];
    unsigned nonempty = 0;
#pragma unroll
    for (int s = 0; s < SETS_PER_WAVE; ++s) {
        const int g    = s >> 1;
        const int base = (s & 1) * PMAX;
        unsigned bits = (unsigned)(bm[g] >> base) & 0x3FFFFFu;
        const int cnt = __builtin_popcount(bits);
        if (bits) nonempty |= (1u << s);
        float acc = 0.0f;
        unsigned bb = bits;
        while (bb) {
            const int p = __builtin_ctz(bb);
            bb &= bb - 1;
            const int src = base + p;
            const int u0 = rl_i(fh[g][0], src);
            const int u1 = rl_i(fh[g][1], src);
            const int u2 = rl_i(fh[g][2], src);
            float t = fdot2i(u0, w01, b1l);
            t = fdot2i(u1, w23, t);
            t = fdot2i(u2, w45, t);
            acc += fmaxf(t, 0.0f);
        }
        hs[s] = acc * (1.0f / fmaxf((float)cnt, 1.0f));  // pool scale folded in
    }

    // --- stage h-bar to LDS as bf16: hb[wave][s][k], lane = k (per-wave) ---
#pragma unroll
    for (int s = 0; s < SETS_PER_WAVE; ++s)
        hb[wave][s][lane] = (unsigned short)bf16_bits(hs[s]);
    wave_lds_sync();

    // --- phase 2: out = hbar @ W2 via MFMA (rows 8..15 dup, unstored).
    // A-frag: lane l holds A[m=lane&15][k=(lane>>4)*8+j] (m89-verified).
    const int Q  = lane >> 4;
    const int sA = lane & 7;
    short8 afrag[2];
#pragma unroll
    for (int kt = 0; kt < 2; ++kt) {
        uint2 p0 = *(const uint2*)&hb[wave][sA][32 * kt + 8 * Q];
        uint2 p1 = *(const uint2*)&hb[wave][sA][32 * kt + 8 * Q + 4];
        union { unsigned u[4]; short8 s8; } cv;
        cv.u[0] = p0.x; cv.u[1] = p0.y; cv.u[2] = p1.x; cv.u[3] = p1.y;
        afrag[kt] = cv.s8;
    }

    float4v acc[8];
#pragma unroll
    for (int nt = 0; nt < 8; ++nt) {
        union { uint4 u4; short8 s8; } f0, f1;
        f0.u4 = *(const uint4*)&w2f[(0 * 8 + nt) * 256 + 4 * lane];
        f1.u4 = *(const uint4*)&w2f[(1 * 8 + nt) * 256 + 4 * lane];
        float4v z = {0.0f, 0.0f, 0.0f, 0.0f};
        acc[nt] = __builtin_amdgcn_mfma_f32_16x16x32_bf16(afrag[0], f0.s8, z, 0, 0, 0);
        acc[nt] = __builtin_amdgcn_mfma_f32_16x16x32_bf16(afrag[1], f1.s8, acc[nt], 0, 0, 0);
    }

    // --- epilogue: + b2 * [cnt>0]; C layout row=(lane>>4)*4+r (=set), col=lane&15
    const int c = lane & 15;
    float b2v[8];
#pragma unroll
    for (int nt = 0; nt < 8; ++nt) b2v[nt] = b2[16 * nt + c];

    if (Q < 2) {
        const unsigned nsh = nonempty >> (4 * Q);
#pragma unroll
        for (int nt = 0; nt < 8; ++nt) {
#pragma unroll
            for (int r = 0; r < 4; ++r) {
                const int s = 4 * Q + r;
                const float f = (float)((nsh >> r) & 1u);
                out[(size_t)(set0 + s) * OUTD + 16 * nt + c] = acc[nt][r] + f * b2v[nt];
            }
        }
    }
}

extern "C" void kernel_launch(void* const* d_in, const int* in_sizes, int n_in,
                              void* d_out, int out_size, void* d_ws, size_t ws_size,
                              hipStream_t stream) {
    const float* player_locs = (const float*)d_in[0];
    const float* actor_locs  = (const float*)d_in[1];
    const float* flags       = (const float*)d_in[2];
    const int*   mask        = (const int*)d_in[3];
    const float* W1          = (const float*)d_in[4];
    const float* b1          = (const float*)d_in[5];
    const float* W2          = (const float*)d_in[6];
    const float* b2          = (const float*)d_in[7];
    float*       out         = (float*)d_out;

    const int B = in_sizes[0] / (PMAX * 2);  // 65536
    const int sets_per_block = WAVES_PER_BLOCK * SETS_PER_WAVE;  // 32
    const int grid = (B + sets_per_block - 1) / sets_per_block;  // 2048

    hipLaunchKernelGGL(set_encoder_kernel, dim3(grid), dim3(256), 0, stream,
                       player_locs, actor_locs, flags, mask, W1, b1, W2, b2, out);
}